// Round 13
// baseline (2668.070 us; speedup 1.0000x reference)
//
#include <hip/hip_runtime.h>
#include <math.h>

// Center-tracking f32 SNN: reductions in f64 (rounded once to f32 at the
// reference's materialization points), elementwise chains in exact-order f32
// round-to-nearest ops (no FMA), constants as f32 values.
// R13: R11 geometry + conv3 row-pair/in-register-pool rewrite (18 FMA/load,
// no LDS/sync) + fc8 folded into conv2 launch. SGPR f64 weights throughout.

__device__ __forceinline__ float axon_step(float A1, float A2, float y1, float y2, float x) {
    return __fadd_rn(__fadd_rn(__fmul_rn(A1, y1), __fmul_rn(A2, y2)), x);
}

__global__ void diag_kernel(float* out, float v, int n) {
    int i = blockIdx.x * 256 + threadIdx.x;
    if (i < n) out[i] = v;
}

__global__ void canary_kernel(float* out, int n) {
    __shared__ float ssum[256];
    float s = 0.f;
    for (int i = threadIdx.x; i < n; i += 256) s += out[i];
    ssum[threadIdx.x] = s;
    __syncthreads();
    for (int k = 128; k > 0; k >>= 1) {
        if (threadIdx.x < k) ssum[threadIdx.x] += ssum[threadIdx.x + k];
        __syncthreads();
    }
    if (threadIdx.x == 0 && ssum[0] == 0.0f) out[0] = 444.0f;
}

// ---- one-time: weights f32 -> f64 (exact) ----
__global__ __launch_bounds__(256) void wcvt_kernel(
        const float* __restrict__ w2, const float* __restrict__ w3,
        const float* __restrict__ w5,
        double* __restrict__ w2d, double* __restrict__ w3d,
        double* __restrict__ w5d) {
    int i = blockIdx.x * 256 + threadIdx.x;
    if (i < 9216)  w2d[i] = (double)w2[i];
    if (i < 18432) w3d[i] = (double)w3[i];
    if (i < 36864) w5d[i] = (double)w5[i];
}

// ---- ann1: frame = sigmoid(conv+b), once ----
__global__ __launch_bounds__(256) void ann1_kernel(
        const float* __restrict__ in, const float* __restrict__ w,
        const float* __restrict__ bias, float* __restrict__ frame) {
    int bid = blockIdx.x;
    int b = bid & 31, co = bid >> 5;
    int tid = threadIdx.x;
    __shared__ double wsh[27];
    if (tid < 27) wsh[tid] = (double)w[co * 27 + tid];
    __syncthreads();
    float bb = bias[co];
    for (int p = tid; p < 900; p += 256) {
        int y = p / 30, x = p % 30;
        double acc = 0.0;
        #pragma unroll
        for (int ci = 0; ci < 3; ++ci) {
            const float* r = in + ((b * 3 + ci) * 32 + y) * 32 + x;
            const double* wp = wsh + ci * 9;
            #pragma unroll
            for (int ky = 0; ky < 3; ++ky)
                acc += (double)r[ky*32+0]*wp[ky*3+0] + (double)r[ky*32+1]*wp[ky*3+1]
                     + (double)r[ky*32+2]*wp[ky*3+2];
        }
        float z = __fadd_rn((float)acc, bb);
        frame[((b * 32 + co) * 30 + y) * 30 + x] =
            (float)(1.0 / (1.0 + exp(-(double)z)));
    }
}

// ---- batched axon2: 25-step exact-order f32 IIR in registers ----
__global__ __launch_bounds__(256) void axon2g_kernel(
        const float2* __restrict__ frame2, float* __restrict__ a2ch,
        float A1, float A2) {
    int g = blockIdx.x * 256 + threadIdx.x;  // 460800 exact
    float2 f = frame2[g];
    float y1a = 0.f, y2a = 0.f, y1b = 0.f, y2b = 0.f;
    #pragma unroll
    for (int k = 0; k < 25; ++k) {
        float v0 = axon_step(A1, A2, y1a, y2a, f.x);
        float v1 = axon_step(A1, A2, y1b, y2b, f.y);
        ((float2*)(a2ch + (size_t)k * 921600))[g] = make_float2(v0, v1);
        y2a = y1a; y1a = v0;
        y2b = y1b; y1b = v1;
    }
}

// ---- fallback per-t axon2 ----
template<bool FIRST>
__global__ __launch_bounds__(256) void axon2_kernel(
        const float2* __restrict__ frame2, float4* __restrict__ y2q,
        float2* __restrict__ a2o2, float A1, float A2) {
    int g = blockIdx.x * 256 + threadIdx.x;
    float2 f = frame2[g];
    float4 y = FIRST ? make_float4(0.f, 0.f, 0.f, 0.f) : y2q[g];
    float v0 = axon_step(A1, A2, y.x, y.y, f.x);
    float v1 = axon_step(A1, A2, y.z, y.w, f.y);
    y2q[g] = make_float4(v0, y.x, v1, y.z);
    a2o2[g] = make_float2(v0, v1);
}

// ---- conv2(f64,SGPR-weights)+b2+LIF2+axon3 -> a3o ; + folded fc8(t-1) ----
// grid: b(32) x cop(16) x sp(2) = 1024 blocks (+32 fc8 blocks if FC8), 256 thr
template<bool FIRST, bool FC8, bool FC8FIRST>
__global__ __launch_bounds__(256) void conv2_kernel(
        const float* __restrict__ a2o, const double* __restrict__ w2d,
        const float* __restrict__ b2,
        float* __restrict__ w2st, float2* __restrict__ y3p,
        float* __restrict__ a3o,
        const float* __restrict__ a8o, const float* __restrict__ w8,
        const float* __restrict__ b8, float* __restrict__ w8st,
        float* __restrict__ outp, int tprev,
        float A1, float A2, float eta_m) {
    int bid = blockIdx.x;
    if (FC8 && bid >= 1024) {
        // ---- fc8 for timestep tprev (32 blocks, 64 lanes) ----
        if (threadIdx.x >= 64) return;
        int b = bid - 1024;
        int lane = threadIdx.x;
        const float* sr = a8o + b * 512;
        for (int o = 0; o < 10; ++o) {
            const float* wr = w8 + o * 512;
            double acc = 0.0;
            #pragma unroll
            for (int i = 0; i < 8; ++i)
                acc += (double)sr[i*64+lane] * (double)wr[i*64+lane];
            #pragma unroll
            for (int off = 32; off > 0; off >>= 1)
                acc += __shfl_down(acc, off);
            if (lane == 0) {
                int idx = b * 10 + o;
                float cur = __fadd_rn((float)acc, b8[o]);
                float wprev = FC8FIRST ? 0.f : w8st[idx];
                float vn = __fadd_rn(__fmul_rn(eta_m, wprev), cur);
                float sn = vn > 1.0f ? 1.0f : 0.0f;
                w8st[idx] = vn > 1.0f ? 0.0f : vn;
                outp[idx * 25 + tprev] = sn;
            }
        }
        return;
    }
    int b = bid & 31, cop = (bid >> 5) & 15, sp = (bid >> 9) & 1;
    int co0 = cop * 2;
    int row0 = sp * 14;
    int p = threadIdx.x;
    if (p >= 196) return;             // 14 rows x 14 x-pairs; no barrier
    int lr = p / 14, xp = p % 14;
    int y = row0 + lr, x = xp * 2;
    double acc0[2] = {0.0, 0.0}, acc1[2] = {0.0, 0.0};
    const double* wbase = w2d + co0 * 288;
    #pragma unroll 2
    for (int ci = 0; ci < 32; ++ci) {
        const float* r = a2o + ((b * 32 + ci) * 30 + y) * 30 + x;
        const double* wp = wbase + ci * 9;   // wave-uniform -> SGPR loads
        #pragma unroll
        for (int ky = 0; ky < 3; ++ky) {
            float2 lo = *(const float2*)(r + ky * 30);
            float2 hi = *(const float2*)(r + ky * 30 + 2);
            double v0 = (double)lo.x, v1 = (double)lo.y;
            double v2 = (double)hi.x, v3 = (double)hi.y;
            #pragma unroll
            for (int j = 0; j < 2; ++j) {
                const double* wj = wp + j * 288 + ky * 3;
                acc0[j] += v0*wj[0] + v1*wj[1] + v2*wj[2];
                acc1[j] += v1*wj[0] + v2*wj[1] + v3*wj[2];
            }
        }
    }
    #pragma unroll
    for (int j = 0; j < 2; ++j) {
        int co = co0 + j;
        float bb = b2[co];
        #pragma unroll
        for (int u = 0; u < 2; ++u) {
            int idx = (b * 32 + co) * 784 + y * 28 + x + u;
            float cur = __fadd_rn((float)(u ? acc1[j] : acc0[j]), bb);
            float wprev = FIRST ? 0.f : w2st[idx];
            float vn = __fadd_rn(__fmul_rn(eta_m, wprev), cur);
            float sn = vn > 1.0f ? 1.0f : 0.0f;
            w2st[idx] = vn > 1.0f ? 0.0f : vn;
            float2 y3 = FIRST ? make_float2(0.f, 0.f) : y3p[idx];
            float yv = axon_step(A1, A2, y3.x, y3.y, sn);
            y3p[idx] = make_float2(yv, y3.x);
            a3o[idx] = yv;
        }
    }
}

// ---- conv3+LIF3+axon4+POOL-IN-REG+axon5 -> a5o [32,64,13,13] ----
// grid: b(32) x coq(16) x sp(2) = 1024 blocks, 128 thr.
// Thread = one 2x2 pool window (2 conv rows x 2 cols) x 4 co: 16 f64 chains,
// 8 float2 loads / 144 FMA per ci, no LDS, no barrier.
template<bool FIRST>
__global__ __launch_bounds__(128) void conv3_kernel(
        const float* __restrict__ a3o, const double* __restrict__ w3d,
        const float* __restrict__ b3,
        float* __restrict__ w3st, float2* __restrict__ y4p,
        float2* __restrict__ y5p, float* __restrict__ a5o,
        float A1, float A2, float eta_m) {
    int bid = blockIdx.x;
    int b = bid & 31, coq = (bid >> 5) & 15, sp = bid >> 9;
    int co0 = coq * 4;
    int q0 = sp ? 7 : 0;
    int npr = sp ? 6 : 7;
    int tid = threadIdx.x;
    if (tid >= npr * 13) return;
    int q = q0 + tid / 13, px = tid % 13;
    int y0 = 2 * q, x0 = 2 * px;
    double acc[4][4];   // [co][r0c0, r0c1, r1c0, r1c1]
    #pragma unroll
    for (int j = 0; j < 4; ++j)
        #pragma unroll
        for (int u = 0; u < 4; ++u) acc[j][u] = 0.0;
    const double* wbase = w3d + co0 * 288;
    #pragma unroll 2
    for (int ci = 0; ci < 32; ++ci) {
        const float* r = a3o + ((b * 32 + ci) * 28 + y0) * 28 + x0;
        const double* wp = wbase + ci * 9;   // wave-uniform -> SGPR loads
        float2 r0a = *(const float2*)(r);      float2 r0b = *(const float2*)(r + 2);
        float2 r1a = *(const float2*)(r + 28); float2 r1b = *(const float2*)(r + 30);
        float2 r2a = *(const float2*)(r + 56); float2 r2b = *(const float2*)(r + 58);
        float2 r3a = *(const float2*)(r + 84); float2 r3b = *(const float2*)(r + 86);
        double v[4][4] = {
            {(double)r0a.x, (double)r0a.y, (double)r0b.x, (double)r0b.y},
            {(double)r1a.x, (double)r1a.y, (double)r1b.x, (double)r1b.y},
            {(double)r2a.x, (double)r2a.y, (double)r2b.x, (double)r2b.y},
            {(double)r3a.x, (double)r3a.y, (double)r3b.x, (double)r3b.y}};
        #pragma unroll
        for (int j = 0; j < 4; ++j) {
            const double* wj = wp + j * 288;
            #pragma unroll
            for (int ky = 0; ky < 3; ++ky) {
                double w0 = wj[ky*3+0], w1 = wj[ky*3+1], w2 = wj[ky*3+2];
                acc[j][0] += v[ky][0]*w0 + v[ky][1]*w1 + v[ky][2]*w2;
                acc[j][1] += v[ky][1]*w0 + v[ky][2]*w1 + v[ky][3]*w2;
                acc[j][2] += v[ky+1][0]*w0 + v[ky+1][1]*w1 + v[ky+1][2]*w2;
                acc[j][3] += v[ky+1][1]*w0 + v[ky+1][2]*w1 + v[ky+1][3]*w2;
            }
        }
    }
    #pragma unroll
    for (int j = 0; j < 4; ++j) {
        int co = co0 + j;
        float bb = b3[co];
        float a4v[4];
        #pragma unroll
        for (int u = 0; u < 4; ++u) {
            int dr = u >> 1, dc = u & 1;
            int idx = (b * 64 + co) * 676 + (y0 + dr) * 26 + x0 + dc;
            float cur = __fadd_rn((float)acc[j][u], bb);
            float wprev = FIRST ? 0.f : w3st[idx];
            float vn = __fadd_rn(__fmul_rn(eta_m, wprev), cur);
            float sn = vn > 1.0f ? 1.0f : 0.0f;
            w3st[idx] = vn > 1.0f ? 0.0f : vn;
            float2 y4 = FIRST ? make_float2(0.f, 0.f) : y4p[idx];
            float a4 = axon_step(A1, A2, y4.x, y4.y, sn);
            y4p[idx] = make_float2(a4, y4.x);
            a4v[u] = a4;
        }
        float m = fmaxf(fmaxf(a4v[0], a4v[1]), fmaxf(a4v[2], a4v[3]));
        int idx5 = (b * 64 + co) * 169 + q * 13 + px;
        float2 y5 = FIRST ? make_float2(0.f, 0.f) : y5p[idx5];
        float yv = axon_step(A1, A2, y5.x, y5.y, m);
        y5p[idx5] = make_float2(yv, y5.x);
        a5o[idx5] = yv;
    }
}

// ---- conv5(f64,SGPR-weights)+b5+LIF5+axon6+maxpool+flatten+axon7 -> a7o ----
// grid: b(32) x co(64) = 2048 blocks, 128 threads; 9 acc chains
template<bool FIRST>
__global__ __launch_bounds__(128) void conv5_kernel(
        const float* __restrict__ a5o, const double* __restrict__ w5d,
        const float* __restrict__ b5,
        float* __restrict__ w5st, float2* __restrict__ y6p,
        float2* __restrict__ y7p, float* __restrict__ a7o,
        float A1, float A2, float eta_m) {
    int bid = blockIdx.x;
    int b = bid & 31, co = bid >> 5;
    int tid = threadIdx.x;
    __shared__ float tile[121];
    const double* wbase = w5d + co * 576;
    if (tid < 121) {
        int y = tid / 11, x = tid % 11;
        double a[9] = {0,0,0,0,0,0,0,0,0};   // 9 indep chains (f64 reassoc safe)
        #pragma unroll 2
        for (int ci = 0; ci < 64; ++ci) {
            const float* r = a5o + (b * 64 + ci) * 169 + y * 13 + x;
            const double* wp = wbase + ci * 9;   // wave-uniform -> SGPR loads
            a[0] += (double)r[0]  * wp[0];
            a[1] += (double)r[1]  * wp[1];
            a[2] += (double)r[2]  * wp[2];
            a[3] += (double)r[13] * wp[3];
            a[4] += (double)r[14] * wp[4];
            a[5] += (double)r[15] * wp[5];
            a[6] += (double)r[26] * wp[6];
            a[7] += (double)r[27] * wp[7];
            a[8] += (double)r[28] * wp[8];
        }
        double acc = ((a[0]+a[1])+(a[2]+a[3])) + ((a[4]+a[5])+(a[6]+a[7])) + a[8];
        int idx = (b * 64 + co) * 121 + tid;
        float cur = __fadd_rn((float)acc, b5[co]);
        float wprev = FIRST ? 0.f : w5st[idx];
        float vn = __fadd_rn(__fmul_rn(eta_m, wprev), cur);
        float sn = vn > 1.0f ? 1.0f : 0.0f;
        w5st[idx] = vn > 1.0f ? 0.0f : vn;
        float2 y6 = FIRST ? make_float2(0.f, 0.f) : y6p[idx];
        float a6 = axon_step(A1, A2, y6.x, y6.y, sn);
        y6p[idx] = make_float2(a6, y6.x);
        tile[tid] = a6;
    }
    __syncthreads();
    if (tid < 25) {
        int py = tid / 5, px = tid % 5;
        const float* tp = tile + (2*py)*11 + 2*px;
        float m = fmaxf(fmaxf(tp[0], tp[1]), fmaxf(tp[11], tp[12]));
        int fi = b * 1600 + co * 25 + tid;
        float2 y7 = FIRST ? make_float2(0.f, 0.f) : y7p[fi];
        float yv = axon_step(A1, A2, y7.x, y7.y, m);
        y7p[fi] = make_float2(yv, y7.x);
        a7o[fi] = yv;
    }
}

// ---- fc7(f64)+b7+LIF7+axon8 -> a8o [32,512] ; 1024 blocks ----
template<bool FIRST>
__global__ __launch_bounds__(256) void fc7_kernel(
        const float* __restrict__ a7o, const float* __restrict__ w7,
        const float* __restrict__ b7,
        float* __restrict__ w7st, float2* __restrict__ y8p,
        float* __restrict__ a8o, float A1, float A2, float eta_m) {
    int bid = blockIdx.x;
    int b = bid & 31, ot = bid >> 5;   // 32 tiles of 16 outputs
    int tid = threadIdx.x;
    int wave = tid >> 6, lane = tid & 63;
    __shared__ float sIn[1600];
    for (int i = tid; i < 1600; i += 256) sIn[i] = a7o[b * 1600 + i];
    __syncthreads();
    for (int oi = 0; oi < 4; ++oi) {
        int o = ot * 16 + wave * 4 + oi;
        const float* wr = w7 + o * 1600;
        double acc = 0.0;
        #pragma unroll
        for (int i = 0; i < 25; ++i)
            acc += (double)sIn[i * 64 + lane] * (double)wr[i * 64 + lane];
        #pragma unroll
        for (int off = 32; off > 0; off >>= 1)
            acc += __shfl_down(acc, off);
        if (lane == 0) {
            int idx = b * 512 + o;
            float cur = __fadd_rn((float)acc, b7[o]);
            float wprev = FIRST ? 0.f : w7st[idx];
            float vn = __fadd_rn(__fmul_rn(eta_m, wprev), cur);
            float sn = vn > 1.0f ? 1.0f : 0.0f;
            w7st[idx] = vn > 1.0f ? 0.0f : vn;
            float2 y8 = FIRST ? make_float2(0.f, 0.f) : y8p[idx];
            float yv = axon_step(A1, A2, y8.x, y8.y, sn);
            y8p[idx] = make_float2(yv, y8.x);
            a8o[idx] = yv;
        }
    }
}

// ---- standalone fc8 (final timestep) ----
template<bool FIRST>
__global__ __launch_bounds__(64) void fc8_kernel(
        const float* __restrict__ a8o, const float* __restrict__ w8,
        const float* __restrict__ b8, float* __restrict__ w8st,
        float* __restrict__ out, int t, float eta_m) {
    int b = blockIdx.x;
    int lane = threadIdx.x;
    const float* sr = a8o + b * 512;
    for (int o = 0; o < 10; ++o) {
        const float* wr = w8 + o * 512;
        double acc = 0.0;
        #pragma unroll
        for (int i = 0; i < 8; ++i)
            acc += (double)sr[i*64+lane] * (double)wr[i*64+lane];
        #pragma unroll
        for (int off = 32; off > 0; off >>= 1)
            acc += __shfl_down(acc, off);
        if (lane == 0) {
            int idx = b * 10 + o;
            float cur = __fadd_rn((float)acc, b8[o]);
            float wprev = FIRST ? 0.f : w8st[idx];
            float vn = __fadd_rn(__fmul_rn(eta_m, wprev), cur);
            float sn = vn > 1.0f ? 1.0f : 0.0f;
            w8st[idx] = vn > 1.0f ? 0.0f : vn;
            out[idx * 25 + t] = sn;
        }
    }
}

extern "C" void kernel_launch(void* const* d_in, const int* in_sizes, int n_in,
                              void* d_out, int out_size, void* d_ws, size_t ws_size,
                              hipStream_t stream) {
    (void)in_sizes; (void)n_in;
    const float* inp = (const float*)d_in[0];
    const float* a1w = (const float*)d_in[1];
    const float* a1b = (const float*)d_in[2];
    const float* w2  = (const float*)d_in[3];
    const float* b2  = (const float*)d_in[4];
    const float* w3  = (const float*)d_in[5];
    const float* b3  = (const float*)d_in[6];
    const float* w5  = (const float*)d_in[7];
    const float* b5  = (const float*)d_in[8];
    const float* w7  = (const float*)d_in[9];
    const float* b7  = (const float*)d_in[10];
    const float* w8  = (const float*)d_in[11];
    const float* b8  = (const float*)d_in[12];
    float* out = (float*)d_out;
    float* ws  = (float*)d_ws;

    const float em = (float)exp(-0.25);
    const float es = (float)exp(-1.0);
    const float A1 = em + es;
    const float A2 = -(em * es);

    // layout (float units); f64 arrays first for 8B alignment
    size_t off = 0;
    auto nf = [&](size_t n) { size_t o = off; off += n; return o; };
    size_t o_w2d   = nf(2*9216);
    size_t o_w3d   = nf(2*18432);
    size_t o_w5d   = nf(2*36864);
    size_t o_frame = nf(921600);
    size_t o_a3o   = nf(802816);
    size_t o_a5o   = nf(346112);
    size_t o_a7o   = nf(51200);
    size_t o_a8o   = nf(16384);
    size_t o_w2st  = nf(802816);
    size_t o_y3p   = nf(2*802816);
    size_t o_w3st  = nf(1384448);
    size_t o_y4p   = nf(2*1384448);
    size_t o_y5p   = nf(2*346112);
    size_t o_w5st  = nf(247808);
    size_t o_y6p   = nf(2*247808);
    size_t o_y7p   = nf(2*51200);
    size_t o_w7st  = nf(16384);
    size_t o_y8p   = nf(2*16384);
    size_t o_w8st  = nf(320);
    size_t commonEnd = off;
    // big mode: a2ch[25] ; fallback: a2o + y2p
    size_t o_a2ch  = commonEnd;                       // 25*921600
    size_t bigEnd  = commonEnd + (size_t)25 * 921600;
    size_t o_a2o   = commonEnd;
    size_t o_y2p   = commonEnd + 921600;
    size_t fbEnd   = commonEnd + 921600 + 2*921600;

    bool big = ws_size >= bigEnd * sizeof(float);
    if (!big && ws_size < fbEnd * sizeof(float)) {
        diag_kernel<<<(out_size + 255) / 256, 256, 0, stream>>>(
            out, 100.0f + (float)(ws_size >> 20), out_size);
        return;
    }

    wcvt_kernel<<<144, 256, 0, stream>>>(w2, w3, w5,
                                         (double*)(ws + o_w2d),
                                         (double*)(ws + o_w3d),
                                         (double*)(ws + o_w5d));
    ann1_kernel<<<1024, 256, 0, stream>>>(inp, a1w, a1b, ws + o_frame);

    if (big) {
        axon2g_kernel<<<1800, 256, 0, stream>>>((const float2*)(ws + o_frame),
                                                ws + o_a2ch, A1, A2);
    }

    const double* w2dp = (const double*)(ws + o_w2d);
    const double* w3dp = (const double*)(ws + o_w3d);
    const double* w5dp = (const double*)(ws + o_w5d);

    for (int t = 0; t < 25; ++t) {
        const float* a2src;
        if (big) {
            a2src = ws + o_a2ch + (size_t)t * 921600;
        } else {
            if (t == 0)
                axon2_kernel<true><<<1800, 256, 0, stream>>>(
                    (const float2*)(ws + o_frame), (float4*)(ws + o_y2p),
                    (float2*)(ws + o_a2o), A1, A2);
            else
                axon2_kernel<false><<<1800, 256, 0, stream>>>(
                    (const float2*)(ws + o_frame), (float4*)(ws + o_y2p),
                    (float2*)(ws + o_a2o), A1, A2);
            a2src = ws + o_a2o;
        }
        // conv2 (+ folded fc8 for t-1)
        if (t == 0) {
            conv2_kernel<true, false, false><<<1024, 256, 0, stream>>>(
                a2src, w2dp, b2, ws + o_w2st, (float2*)(ws + o_y3p), ws + o_a3o,
                ws + o_a8o, w8, b8, ws + o_w8st, out, -1, A1, A2, em);
        } else if (t == 1) {
            conv2_kernel<false, true, true><<<1056, 256, 0, stream>>>(
                a2src, w2dp, b2, ws + o_w2st, (float2*)(ws + o_y3p), ws + o_a3o,
                ws + o_a8o, w8, b8, ws + o_w8st, out, t - 1, A1, A2, em);
        } else {
            conv2_kernel<false, true, false><<<1056, 256, 0, stream>>>(
                a2src, w2dp, b2, ws + o_w2st, (float2*)(ws + o_y3p), ws + o_a3o,
                ws + o_a8o, w8, b8, ws + o_w8st, out, t - 1, A1, A2, em);
        }
        if (t == 0) {
            conv3_kernel<true><<<1024, 128, 0, stream>>>(ws + o_a3o, w3dp, b3,
                ws + o_w3st, (float2*)(ws + o_y4p), (float2*)(ws + o_y5p), ws + o_a5o, A1, A2, em);
            conv5_kernel<true><<<2048, 128, 0, stream>>>(ws + o_a5o, w5dp, b5,
                ws + o_w5st, (float2*)(ws + o_y6p), (float2*)(ws + o_y7p), ws + o_a7o, A1, A2, em);
            fc7_kernel<true><<<1024, 256, 0, stream>>>(ws + o_a7o, w7, b7,
                ws + o_w7st, (float2*)(ws + o_y8p), ws + o_a8o, A1, A2, em);
        } else {
            conv3_kernel<false><<<1024, 128, 0, stream>>>(ws + o_a3o, w3dp, b3,
                ws + o_w3st, (float2*)(ws + o_y4p), (float2*)(ws + o_y5p), ws + o_a5o, A1, A2, em);
            conv5_kernel<false><<<2048, 128, 0, stream>>>(ws + o_a5o, w5dp, b5,
                ws + o_w5st, (float2*)(ws + o_y6p), (float2*)(ws + o_y7p), ws + o_a7o, A1, A2, em);
            fc7_kernel<false><<<1024, 256, 0, stream>>>(ws + o_a7o, w7, b7,
                ws + o_w7st, (float2*)(ws + o_y8p), ws + o_a8o, A1, A2, em);
        }
    }
    // final fc8 (t = 24)
    fc8_kernel<false><<<32, 64, 0, stream>>>(ws + o_a8o, w8, b8, ws + o_w8st,
                                             out, 24, em);

    canary_kernel<<<1, 256, 0, stream>>>(out, out_size);
}

// Round 14
// 2322.088 us; speedup vs baseline: 1.1490x; 1.1490x over previous
//
#include <hip/hip_runtime.h>
#include <math.h>

// Center-tracking f32 SNN: reductions in f64 (rounded once to f32 at the
// reference's materialization points), elementwise chains in exact-order f32
// round-to-nearest ops (no FMA), constants as f32 values.
// R14: exact R11 structure (best: 2481us) + fc8(t-1) folded into conv2 launch.

__device__ __forceinline__ float axon_step(float A1, float A2, float y1, float y2, float x) {
    return __fadd_rn(__fadd_rn(__fmul_rn(A1, y1), __fmul_rn(A2, y2)), x);
}

__global__ void diag_kernel(float* out, float v, int n) {
    int i = blockIdx.x * 256 + threadIdx.x;
    if (i < n) out[i] = v;
}

__global__ void canary_kernel(float* out, int n) {
    __shared__ float ssum[256];
    float s = 0.f;
    for (int i = threadIdx.x; i < n; i += 256) s += out[i];
    ssum[threadIdx.x] = s;
    __syncthreads();
    for (int k = 128; k > 0; k >>= 1) {
        if (threadIdx.x < k) ssum[threadIdx.x] += ssum[threadIdx.x + k];
        __syncthreads();
    }
    if (threadIdx.x == 0 && ssum[0] == 0.0f) out[0] = 444.0f;
}

// ---- one-time: weights f32 -> f64 (exact) ----
__global__ __launch_bounds__(256) void wcvt_kernel(
        const float* __restrict__ w2, const float* __restrict__ w3,
        const float* __restrict__ w5,
        double* __restrict__ w2d, double* __restrict__ w3d,
        double* __restrict__ w5d) {
    int i = blockIdx.x * 256 + threadIdx.x;
    if (i < 9216)  w2d[i] = (double)w2[i];
    if (i < 18432) w3d[i] = (double)w3[i];
    if (i < 36864) w5d[i] = (double)w5[i];
}

// ---- ann1: frame = sigmoid(conv+b), once ----
__global__ __launch_bounds__(256) void ann1_kernel(
        const float* __restrict__ in, const float* __restrict__ w,
        const float* __restrict__ bias, float* __restrict__ frame) {
    int bid = blockIdx.x;
    int b = bid & 31, co = bid >> 5;
    int tid = threadIdx.x;
    __shared__ double wsh[27];
    if (tid < 27) wsh[tid] = (double)w[co * 27 + tid];
    __syncthreads();
    float bb = bias[co];
    for (int p = tid; p < 900; p += 256) {
        int y = p / 30, x = p % 30;
        double acc = 0.0;
        #pragma unroll
        for (int ci = 0; ci < 3; ++ci) {
            const float* r = in + ((b * 3 + ci) * 32 + y) * 32 + x;
            const double* wp = wsh + ci * 9;
            #pragma unroll
            for (int ky = 0; ky < 3; ++ky)
                acc += (double)r[ky*32+0]*wp[ky*3+0] + (double)r[ky*32+1]*wp[ky*3+1]
                     + (double)r[ky*32+2]*wp[ky*3+2];
        }
        float z = __fadd_rn((float)acc, bb);
        frame[((b * 32 + co) * 30 + y) * 30 + x] =
            (float)(1.0 / (1.0 + exp(-(double)z)));
    }
}

// ---- batched axon2: 25-step exact-order f32 IIR in registers ----
__global__ __launch_bounds__(256) void axon2g_kernel(
        const float2* __restrict__ frame2, float* __restrict__ a2ch,
        float A1, float A2) {
    int g = blockIdx.x * 256 + threadIdx.x;  // 460800 exact
    float2 f = frame2[g];
    float y1a = 0.f, y2a = 0.f, y1b = 0.f, y2b = 0.f;
    #pragma unroll
    for (int k = 0; k < 25; ++k) {
        float v0 = axon_step(A1, A2, y1a, y2a, f.x);
        float v1 = axon_step(A1, A2, y1b, y2b, f.y);
        ((float2*)(a2ch + (size_t)k * 921600))[g] = make_float2(v0, v1);
        y2a = y1a; y1a = v0;
        y2b = y1b; y1b = v1;
    }
}

// ---- fallback per-t axon2 ----
template<bool FIRST>
__global__ __launch_bounds__(256) void axon2_kernel(
        const float2* __restrict__ frame2, float4* __restrict__ y2q,
        float2* __restrict__ a2o2, float A1, float A2) {
    int g = blockIdx.x * 256 + threadIdx.x;
    float2 f = frame2[g];
    float4 y = FIRST ? make_float4(0.f, 0.f, 0.f, 0.f) : y2q[g];
    float v0 = axon_step(A1, A2, y.x, y.y, f.x);
    float v1 = axon_step(A1, A2, y.z, y.w, f.y);
    y2q[g] = make_float4(v0, y.x, v1, y.z);
    a2o2[g] = make_float2(v0, v1);
}

// ---- conv2(f64,SGPR-weights)+b2+LIF2+axon3 -> a3o ; + folded fc8(t-1) ----
// grid: b(32) x cop(16) x sp(2) = 1024 blocks (+32 fc8 blocks if FC8), 256 thr
template<bool FIRST, bool FC8, bool FC8FIRST>
__global__ __launch_bounds__(256) void conv2_kernel(
        const float* __restrict__ a2o, const double* __restrict__ w2d,
        const float* __restrict__ b2,
        float* __restrict__ w2st, float2* __restrict__ y3p,
        float* __restrict__ a3o,
        const float* __restrict__ a8o, const float* __restrict__ w8,
        const float* __restrict__ b8, float* __restrict__ w8st,
        float* __restrict__ outp, int tprev,
        float A1, float A2, float eta_m) {
    int bid = blockIdx.x;
    if (FC8 && bid >= 1024) {
        // ---- fc8 for timestep tprev (32 blocks, lanes 0..63) ----
        if (threadIdx.x >= 64) return;
        int b = bid - 1024;
        int lane = threadIdx.x;
        const float* sr = a8o + b * 512;
        for (int o = 0; o < 10; ++o) {
            const float* wr = w8 + o * 512;
            double acc = 0.0;
            #pragma unroll
            for (int i = 0; i < 8; ++i)
                acc += (double)sr[i*64+lane] * (double)wr[i*64+lane];
            #pragma unroll
            for (int off = 32; off > 0; off >>= 1)
                acc += __shfl_down(acc, off);
            if (lane == 0) {
                int idx = b * 10 + o;
                float cur = __fadd_rn((float)acc, b8[o]);
                float wprev = FC8FIRST ? 0.f : w8st[idx];
                float vn = __fadd_rn(__fmul_rn(eta_m, wprev), cur);
                float sn = vn > 1.0f ? 1.0f : 0.0f;
                w8st[idx] = vn > 1.0f ? 0.0f : vn;
                outp[idx * 25 + tprev] = sn;
            }
        }
        return;
    }
    int b = bid & 31, cop = (bid >> 5) & 15, sp = (bid >> 9) & 1;
    int co0 = cop * 2;
    int row0 = sp * 14;
    int p = threadIdx.x;
    if (p >= 196) return;             // 14 rows x 14 x-pairs; no barrier
    int lr = p / 14, xp = p % 14;
    int y = row0 + lr, x = xp * 2;
    double acc0[2] = {0.0, 0.0}, acc1[2] = {0.0, 0.0};
    const double* wbase = w2d + co0 * 288;
    #pragma unroll 2
    for (int ci = 0; ci < 32; ++ci) {
        const float* r = a2o + ((b * 32 + ci) * 30 + y) * 30 + x;
        const double* wp = wbase + ci * 9;   // wave-uniform -> SGPR loads
        #pragma unroll
        for (int ky = 0; ky < 3; ++ky) {
            float2 lo = *(const float2*)(r + ky * 30);
            float2 hi = *(const float2*)(r + ky * 30 + 2);
            double v0 = (double)lo.x, v1 = (double)lo.y;
            double v2 = (double)hi.x, v3 = (double)hi.y;
            #pragma unroll
            for (int j = 0; j < 2; ++j) {
                const double* wj = wp + j * 288 + ky * 3;
                acc0[j] += v0*wj[0] + v1*wj[1] + v2*wj[2];
                acc1[j] += v1*wj[0] + v2*wj[1] + v3*wj[2];
            }
        }
    }
    #pragma unroll
    for (int j = 0; j < 2; ++j) {
        int co = co0 + j;
        float bb = b2[co];
        #pragma unroll
        for (int u = 0; u < 2; ++u) {
            int idx = (b * 32 + co) * 784 + y * 28 + x + u;
            float cur = __fadd_rn((float)(u ? acc1[j] : acc0[j]), bb);
            float wprev = FIRST ? 0.f : w2st[idx];
            float vn = __fadd_rn(__fmul_rn(eta_m, wprev), cur);
            float sn = vn > 1.0f ? 1.0f : 0.0f;
            w2st[idx] = vn > 1.0f ? 0.0f : vn;
            float2 y3 = FIRST ? make_float2(0.f, 0.f) : y3p[idx];
            float yv = axon_step(A1, A2, y3.x, y3.y, sn);
            y3p[idx] = make_float2(yv, y3.x);
            a3o[idx] = yv;
        }
    }
}

// ---- conv3(f64,SGPR-weights)+b3+LIF3+axon4+maxpool+axon5 -> a5o ----
// grid: b(32) x coq(16) x sp(2) = 1024 blocks, 256 thr; 4 co x 2 x per thread
template<bool FIRST>
__global__ __launch_bounds__(256) void conv3_kernel(
        const float* __restrict__ a3o, const double* __restrict__ w3d,
        const float* __restrict__ b3,
        float* __restrict__ w3st, float2* __restrict__ y4p,
        float2* __restrict__ y5p, float* __restrict__ a5o,
        float A1, float A2, float eta_m) {
    int bid = blockIdx.x;
    int b = bid & 31, coq = (bid >> 5) & 15, sp = bid >> 9;
    int co0 = coq * 4;
    int row0 = sp ? 14 : 0;
    int nrow = sp ? 12 : 14;
    int pr0  = sp ? 7 : 0;
    int npr  = sp ? 6 : 7;
    int tid = threadIdx.x;
    __shared__ float tile[4 * 364];   // [4 co][<=14 rows][26]  (pool staging only)
    int npair = nrow * 13;
    const double* wbase = w3d + co0 * 288;
    for (int p = tid; p < npair; p += 256) {
        int lr = p / 13, xp = p % 13;
        int y = row0 + lr, x = xp * 2;
        double acc0[4] = {0.0, 0.0, 0.0, 0.0};
        double acc1[4] = {0.0, 0.0, 0.0, 0.0};
        #pragma unroll 2
        for (int ci = 0; ci < 32; ++ci) {
            const float* r = a3o + ((b * 32 + ci) * 28 + y) * 28 + x;
            const double* wp = wbase + ci * 9;   // wave-uniform -> SGPR loads
            #pragma unroll
            for (int ky = 0; ky < 3; ++ky) {
                float2 lo = *(const float2*)(r + ky * 28);
                float2 hi = *(const float2*)(r + ky * 28 + 2);
                double v0 = (double)lo.x, v1 = (double)lo.y;
                double v2 = (double)hi.x, v3 = (double)hi.y;
                #pragma unroll
                for (int j = 0; j < 4; ++j) {
                    const double* wj = wp + j * 288 + ky * 3;
                    acc0[j] += v0*wj[0] + v1*wj[1] + v2*wj[2];
                    acc1[j] += v1*wj[0] + v2*wj[1] + v3*wj[2];
                }
            }
        }
        #pragma unroll
        for (int j = 0; j < 4; ++j) {
            int co = co0 + j;
            float bb = b3[co];
            #pragma unroll
            for (int u = 0; u < 2; ++u) {
                int idx = (b * 64 + co) * 676 + y * 26 + x + u;
                float cur = __fadd_rn((float)(u ? acc1[j] : acc0[j]), bb);
                float wprev = FIRST ? 0.f : w3st[idx];
                float vn = __fadd_rn(__fmul_rn(eta_m, wprev), cur);
                float sn = vn > 1.0f ? 1.0f : 0.0f;
                w3st[idx] = vn > 1.0f ? 0.0f : vn;
                float2 y4 = FIRST ? make_float2(0.f, 0.f) : y4p[idx];
                float a4 = axon_step(A1, A2, y4.x, y4.y, sn);
                y4p[idx] = make_float2(a4, y4.x);
                tile[j * 364 + lr * 26 + x + u] = a4;
            }
        }
    }
    __syncthreads();
    int npool = npr * 13 * 4;
    for (int q = tid; q < npool; q += 256) {
        int j = q / (npr * 13), pp = q % (npr * 13);
        int pry = pp / 13, px = pp % 13;
        int pr = pr0 + pry;
        int lr = 2 * pr - row0;
        const float* tp = tile + j * 364 + lr * 26 + 2 * px;
        float m = fmaxf(fmaxf(tp[0], tp[1]), fmaxf(tp[26], tp[27]));
        int idx = (b * 64 + co0 + j) * 169 + pr * 13 + px;
        float2 y5 = FIRST ? make_float2(0.f, 0.f) : y5p[idx];
        float yv = axon_step(A1, A2, y5.x, y5.y, m);
        y5p[idx] = make_float2(yv, y5.x);
        a5o[idx] = yv;
    }
}

// ---- conv5(f64,SGPR-weights)+b5+LIF5+axon6+maxpool+flatten+axon7 -> a7o ----
// grid: b(32) x co(64) = 2048 blocks, 128 threads; 9 acc chains
template<bool FIRST>
__global__ __launch_bounds__(128) void conv5_kernel(
        const float* __restrict__ a5o, const double* __restrict__ w5d,
        const float* __restrict__ b5,
        float* __restrict__ w5st, float2* __restrict__ y6p,
        float2* __restrict__ y7p, float* __restrict__ a7o,
        float A1, float A2, float eta_m) {
    int bid = blockIdx.x;
    int b = bid & 31, co = bid >> 5;
    int tid = threadIdx.x;
    __shared__ float tile[121];
    const double* wbase = w5d + co * 576;
    if (tid < 121) {
        int y = tid / 11, x = tid % 11;
        double a[9] = {0,0,0,0,0,0,0,0,0};   // 9 indep chains (f64 reassoc safe)
        #pragma unroll 2
        for (int ci = 0; ci < 64; ++ci) {
            const float* r = a5o + (b * 64 + ci) * 169 + y * 13 + x;
            const double* wp = wbase + ci * 9;   // wave-uniform -> SGPR loads
            a[0] += (double)r[0]  * wp[0];
            a[1] += (double)r[1]  * wp[1];
            a[2] += (double)r[2]  * wp[2];
            a[3] += (double)r[13] * wp[3];
            a[4] += (double)r[14] * wp[4];
            a[5] += (double)r[15] * wp[5];
            a[6] += (double)r[26] * wp[6];
            a[7] += (double)r[27] * wp[7];
            a[8] += (double)r[28] * wp[8];
        }
        double acc = ((a[0]+a[1])+(a[2]+a[3])) + ((a[4]+a[5])+(a[6]+a[7])) + a[8];
        int idx = (b * 64 + co) * 121 + tid;
        float cur = __fadd_rn((float)acc, b5[co]);
        float wprev = FIRST ? 0.f : w5st[idx];
        float vn = __fadd_rn(__fmul_rn(eta_m, wprev), cur);
        float sn = vn > 1.0f ? 1.0f : 0.0f;
        w5st[idx] = vn > 1.0f ? 0.0f : vn;
        float2 y6 = FIRST ? make_float2(0.f, 0.f) : y6p[idx];
        float a6 = axon_step(A1, A2, y6.x, y6.y, sn);
        y6p[idx] = make_float2(a6, y6.x);
        tile[tid] = a6;
    }
    __syncthreads();
    if (tid < 25) {
        int py = tid / 5, px = tid % 5;
        const float* tp = tile + (2*py)*11 + 2*px;
        float m = fmaxf(fmaxf(tp[0], tp[1]), fmaxf(tp[11], tp[12]));
        int fi = b * 1600 + co * 25 + tid;
        float2 y7 = FIRST ? make_float2(0.f, 0.f) : y7p[fi];
        float yv = axon_step(A1, A2, y7.x, y7.y, m);
        y7p[fi] = make_float2(yv, y7.x);
        a7o[fi] = yv;
    }
}

// ---- fc7(f64)+b7+LIF7+axon8 -> a8o [32,512] ; 1024 blocks ----
template<bool FIRST>
__global__ __launch_bounds__(256) void fc7_kernel(
        const float* __restrict__ a7o, const float* __restrict__ w7,
        const float* __restrict__ b7,
        float* __restrict__ w7st, float2* __restrict__ y8p,
        float* __restrict__ a8o, float A1, float A2, float eta_m) {
    int bid = blockIdx.x;
    int b = bid & 31, ot = bid >> 5;   // 32 tiles of 16 outputs
    int tid = threadIdx.x;
    int wave = tid >> 6, lane = tid & 63;
    __shared__ float sIn[1600];
    for (int i = tid; i < 1600; i += 256) sIn[i] = a7o[b * 1600 + i];
    __syncthreads();
    for (int oi = 0; oi < 4; ++oi) {
        int o = ot * 16 + wave * 4 + oi;
        const float* wr = w7 + o * 1600;
        double acc = 0.0;
        #pragma unroll
        for (int i = 0; i < 25; ++i)
            acc += (double)sIn[i * 64 + lane] * (double)wr[i * 64 + lane];
        #pragma unroll
        for (int off = 32; off > 0; off >>= 1)
            acc += __shfl_down(acc, off);
        if (lane == 0) {
            int idx = b * 512 + o;
            float cur = __fadd_rn((float)acc, b7[o]);
            float wprev = FIRST ? 0.f : w7st[idx];
            float vn = __fadd_rn(__fmul_rn(eta_m, wprev), cur);
            float sn = vn > 1.0f ? 1.0f : 0.0f;
            w7st[idx] = vn > 1.0f ? 0.0f : vn;
            float2 y8 = FIRST ? make_float2(0.f, 0.f) : y8p[idx];
            float yv = axon_step(A1, A2, y8.x, y8.y, sn);
            y8p[idx] = make_float2(yv, y8.x);
            a8o[idx] = yv;
        }
    }
}

// ---- standalone fc8 (final timestep) ----
template<bool FIRST>
__global__ __launch_bounds__(64) void fc8_kernel(
        const float* __restrict__ a8o, const float* __restrict__ w8,
        const float* __restrict__ b8, float* __restrict__ w8st,
        float* __restrict__ out, int t, float eta_m) {
    int b = blockIdx.x;
    int lane = threadIdx.x;
    const float* sr = a8o + b * 512;
    for (int o = 0; o < 10; ++o) {
        const float* wr = w8 + o * 512;
        double acc = 0.0;
        #pragma unroll
        for (int i = 0; i < 8; ++i)
            acc += (double)sr[i*64+lane] * (double)wr[i*64+lane];
        #pragma unroll
        for (int off = 32; off > 0; off >>= 1)
            acc += __shfl_down(acc, off);
        if (lane == 0) {
            int idx = b * 10 + o;
            float cur = __fadd_rn((float)acc, b8[o]);
            float wprev = FIRST ? 0.f : w8st[idx];
            float vn = __fadd_rn(__fmul_rn(eta_m, wprev), cur);
            float sn = vn > 1.0f ? 1.0f : 0.0f;
            w8st[idx] = vn > 1.0f ? 0.0f : vn;
            out[idx * 25 + t] = sn;
        }
    }
}

extern "C" void kernel_launch(void* const* d_in, const int* in_sizes, int n_in,
                              void* d_out, int out_size, void* d_ws, size_t ws_size,
                              hipStream_t stream) {
    (void)in_sizes; (void)n_in;
    const float* inp = (const float*)d_in[0];
    const float* a1w = (const float*)d_in[1];
    const float* a1b = (const float*)d_in[2];
    const float* w2  = (const float*)d_in[3];
    const float* b2  = (const float*)d_in[4];
    const float* w3  = (const float*)d_in[5];
    const float* b3  = (const float*)d_in[6];
    const float* w5  = (const float*)d_in[7];
    const float* b5  = (const float*)d_in[8];
    const float* w7  = (const float*)d_in[9];
    const float* b7  = (const float*)d_in[10];
    const float* w8  = (const float*)d_in[11];
    const float* b8  = (const float*)d_in[12];
    float* out = (float*)d_out;
    float* ws  = (float*)d_ws;

    const float em = (float)exp(-0.25);
    const float es = (float)exp(-1.0);
    const float A1 = em + es;
    const float A2 = -(em * es);

    // layout (float units); f64 arrays first for 8B alignment
    size_t off = 0;
    auto nf = [&](size_t n) { size_t o = off; off += n; return o; };
    size_t o_w2d   = nf(2*9216);
    size_t o_w3d   = nf(2*18432);
    size_t o_w5d   = nf(2*36864);
    size_t o_frame = nf(921600);
    size_t o_a3o   = nf(802816);
    size_t o_a5o   = nf(346112);
    size_t o_a7o   = nf(51200);
    size_t o_a8o   = nf(16384);
    size_t o_w2st  = nf(802816);
    size_t o_y3p   = nf(2*802816);
    size_t o_w3st  = nf(1384448);
    size_t o_y4p   = nf(2*1384448);
    size_t o_y5p   = nf(2*346112);
    size_t o_w5st  = nf(247808);
    size_t o_y6p   = nf(2*247808);
    size_t o_y7p   = nf(2*51200);
    size_t o_w7st  = nf(16384);
    size_t o_y8p   = nf(2*16384);
    size_t o_w8st  = nf(320);
    size_t commonEnd = off;
    // big mode: a2ch[25] ; fallback: a2o + y2p
    size_t o_a2ch  = commonEnd;                       // 25*921600
    size_t bigEnd  = commonEnd + (size_t)25 * 921600;
    size_t o_a2o   = commonEnd;
    size_t o_y2p   = commonEnd + 921600;
    size_t fbEnd   = commonEnd + 921600 + 2*921600;

    bool big = ws_size >= bigEnd * sizeof(float);
    if (!big && ws_size < fbEnd * sizeof(float)) {
        diag_kernel<<<(out_size + 255) / 256, 256, 0, stream>>>(
            out, 100.0f + (float)(ws_size >> 20), out_size);
        return;
    }

    wcvt_kernel<<<144, 256, 0, stream>>>(w2, w3, w5,
                                         (double*)(ws + o_w2d),
                                         (double*)(ws + o_w3d),
                                         (double*)(ws + o_w5d));
    ann1_kernel<<<1024, 256, 0, stream>>>(inp, a1w, a1b, ws + o_frame);

    if (big) {
        axon2g_kernel<<<1800, 256, 0, stream>>>((const float2*)(ws + o_frame),
                                                ws + o_a2ch, A1, A2);
    }

    const double* w2dp = (const double*)(ws + o_w2d);
    const double* w3dp = (const double*)(ws + o_w3d);
    const double* w5dp = (const double*)(ws + o_w5d);

    for (int t = 0; t < 25; ++t) {
        const float* a2src;
        if (big) {
            a2src = ws + o_a2ch + (size_t)t * 921600;
        } else {
            if (t == 0)
                axon2_kernel<true><<<1800, 256, 0, stream>>>(
                    (const float2*)(ws + o_frame), (float4*)(ws + o_y2p),
                    (float2*)(ws + o_a2o), A1, A2);
            else
                axon2_kernel<false><<<1800, 256, 0, stream>>>(
                    (const float2*)(ws + o_frame), (float4*)(ws + o_y2p),
                    (float2*)(ws + o_a2o), A1, A2);
            a2src = ws + o_a2o;
        }
        // conv2 (+ folded fc8 for t-1)
        if (t == 0) {
            conv2_kernel<true, false, false><<<1024, 256, 0, stream>>>(
                a2src, w2dp, b2, ws + o_w2st, (float2*)(ws + o_y3p), ws + o_a3o,
                ws + o_a8o, w8, b8, ws + o_w8st, out, -1, A1, A2, em);
        } else if (t == 1) {
            conv2_kernel<false, true, true><<<1056, 256, 0, stream>>>(
                a2src, w2dp, b2, ws + o_w2st, (float2*)(ws + o_y3p), ws + o_a3o,
                ws + o_a8o, w8, b8, ws + o_w8st, out, t - 1, A1, A2, em);
        } else {
            conv2_kernel<false, true, false><<<1056, 256, 0, stream>>>(
                a2src, w2dp, b2, ws + o_w2st, (float2*)(ws + o_y3p), ws + o_a3o,
                ws + o_a8o, w8, b8, ws + o_w8st, out, t - 1, A1, A2, em);
        }
        if (t == 0) {
            conv3_kernel<true><<<1024, 256, 0, stream>>>(ws + o_a3o, w3dp, b3,
                ws + o_w3st, (float2*)(ws + o_y4p), (float2*)(ws + o_y5p), ws + o_a5o, A1, A2, em);
            conv5_kernel<true><<<2048, 128, 0, stream>>>(ws + o_a5o, w5dp, b5,
                ws + o_w5st, (float2*)(ws + o_y6p), (float2*)(ws + o_y7p), ws + o_a7o, A1, A2, em);
            fc7_kernel<true><<<1024, 256, 0, stream>>>(ws + o_a7o, w7, b7,
                ws + o_w7st, (float2*)(ws + o_y8p), ws + o_a8o, A1, A2, em);
        } else {
            conv3_kernel<false><<<1024, 256, 0, stream>>>(ws + o_a3o, w3dp, b3,
                ws + o_w3st, (float2*)(ws + o_y4p), (float2*)(ws + o_y5p), ws + o_a5o, A1, A2, em);
            conv5_kernel<false><<<2048, 128, 0, stream>>>(ws + o_a5o, w5dp, b5,
                ws + o_w5st, (float2*)(ws + o_y6p), (float2*)(ws + o_y7p), ws + o_a7o, A1, A2, em);
            fc7_kernel<false><<<1024, 256, 0, stream>>>(ws + o_a7o, w7, b7,
                ws + o_w7st, (float2*)(ws + o_y8p), ws + o_a8o, A1, A2, em);
        }
    }
    // final fc8 (t = 24)
    fc8_kernel<false><<<32, 64, 0, stream>>>(ws + o_a8o, w8, b8, ws + o_w8st,
                                             out, 24, em);

    canary_kernel<<<1, 256, 0, stream>>>(out, out_size);
}